// Round 4
// baseline (508.379 us; speedup 1.0000x reference)
//
#include <hip/hip_runtime.h>
#include <hip/hip_bf16.h>
#include <cstdint>

typedef __attribute__((ext_vector_type(8))) short short8;
typedef __attribute__((ext_vector_type(4))) float f32x4;
typedef unsigned short ushort_t;

#define MM 8192
#define NN 4096
#define KK 4096

#define BM 128
#define BN 128
#define BK 64
#define NT (KK / BK)  // 64 K-tiles

#define MFMA_BF16 __builtin_amdgcn_mfma_f32_16x16x32_bf16

// fp32 -> bf16 round-to-nearest-even (inputs are finite)
__device__ __forceinline__ ushort_t f2bf(float f) {
  uint32_t u = __builtin_bit_cast(uint32_t, f);
  u = (u + 0x7FFFu + ((u >> 16) & 1u)) >> 16;
  return (ushort_t)u;
}

// fused activation chain: leaky_relu -> +y -> mish -> hardswish + 0.5
__device__ __forceinline__ float epilogue(float v, float yv) {
  v = fmaxf(v, 0.01f * v);  // leaky relu
  v += yv;
  const float vc = fminf(v, 15.f);
  const float t = __builtin_amdgcn_exp2f(vc * 1.44269504f);  // e^vc
  const float d = t * t + 2.f * t;
  const float mi = v * d * __builtin_amdgcn_rcpf(d + 2.f);   // mish
  const float r6 = fminf(fmaxf(mi + 3.f, 0.f), 6.f);
  return mi * r6 * (1.f / 6.f) + 0.5f;                       // hardswish + 0.5
}

// async 16B global->LDS (LDS dest is wave-uniform base + lane*16)
__device__ __forceinline__ void gload_lds16(const void* g, void* l) {
  __builtin_amdgcn_global_load_lds(
      (const __attribute__((address_space(1))) unsigned int*)g,
      (__attribute__((address_space(3))) unsigned int*)l, 16, 0, 0);
}

#define CVT_BLOCKS ((MM * KK) / (256 * 8))      // 16384
#define WT_BLOCKS ((NN / 32) * (KK / 32))       // 16384

// ---------------- merged prep: X convert (bid<CVT_BLOCKS) + W transpose ----------------
template <int DO_X>
__global__ void prep_kernel(const float* __restrict__ X, ushort_t* __restrict__ XB,
                            const float* __restrict__ W, ushort_t* __restrict__ WT) {
  __shared__ float t[32][33];
  const int bid = blockIdx.x;
  const int tid = threadIdx.x;
  if (DO_X && bid < CVT_BLOCKS) {
    const size_t i = ((size_t)bid * 256 + tid) * 8;
    f32x4 v0 = __builtin_nontemporal_load(reinterpret_cast<const f32x4*>(&X[i]));
    f32x4 v1 = __builtin_nontemporal_load(reinterpret_cast<const f32x4*>(&X[i + 4]));
    short8 o;
    o[0] = (short)f2bf(v0[0]); o[1] = (short)f2bf(v0[1]);
    o[2] = (short)f2bf(v0[2]); o[3] = (short)f2bf(v0[3]);
    o[4] = (short)f2bf(v1[0]); o[5] = (short)f2bf(v1[1]);
    o[6] = (short)f2bf(v1[2]); o[7] = (short)f2bf(v1[3]);
    *reinterpret_cast<short8*>(&XB[i]) = o;
  } else {
    const int b2 = DO_X ? (bid - CVT_BLOCKS) : bid;
    const int n0 = (b2 & 127) * 32, k0 = (b2 >> 7) * 32;
    const int tx = tid & 31, ty = tid >> 5;  // 32 x 8
#pragma unroll
    for (int i = ty; i < 32; i += 8)
      t[i][tx] = __builtin_nontemporal_load(&W[(size_t)(k0 + i) * NN + n0 + tx]);
    __syncthreads();
#pragma unroll
    for (int i = ty; i < 32; i += 8)
      WT[(size_t)(n0 + i) * KK + k0 + tx] = f2bf(t[tx][i]);
  }
}

// ---------------- main fused GEMM: 256x128 tile, region-rotation, 2 blocks/CU ---------
// R4: R1-R3 (1 block/CU, 2-wave/SIMD lockstep) were structurally additive
// (LDS + MFMA + barriers serialize; 3 nulls on scheduling details). This round
// combines the two proven ingredients: counted-vmcnt rotation (no full drains)
// + 16 waves/CU TLP (R0's hidden weapon, m114 co-scheduling).
//   tile 256x128, BK=64, 8 waves (4M x 2N), per-wave 64x64 (acc = 64 AGPR).
//   LDS: SINGLE buffer A[256][64] + B[128][64] = 48 KB -> 2 blocks/CU.
//   Regions by 32-row bands: A0 = bands{0,2,4,6}, A1 = {1,3,5,7} (of 8);
//   B0 = {0,2}, B1 = {1,3} (of 4). Wave (wmi,wni) phase quadrant (qm,qn)
//   reads A rows wmi*64+qm*32+.., B rows wni*64+qn*32+.. -> region = qm/qn.
// Phases per tile t: p1=(0,0) reads a<-A0,b0<-B0, stages A1(t);
//   p2=(0,1) reads b1<-B1, stages B0(t+1); p3=(1,1)+(1,0) reads a<-A1,
//   stages A0(t+1)+B1(t+1), 16 MFMA. b0 held in regs p1->p3 (B0 read once).
// vmcnt guards (pre-closing-barrier; 6 gloads/wave/tile, in-order retire):
//   p1-close vmcnt(2) retires B1(t)   [read at p2]
//   p2-close vmcnt(1) retires A1(t)   [read at p3]
//   p3-close vmcnt(1) retires B0,A0(t+1) [read at t+1.p1]; keeps B1(t+1).
// WAR: every region's overwrite issues >=1 barrier after its last lgkm-drained
// read (A1(t)@p1 vs t-1.p3; B0'@p2 vs p1; A0'@p3 vs p1; B1'@p3 vs p2). Tail
// stages wrap mod K (wasted but hazard-free, regions have no further reads).
#define STAGE_A(H, ktv)                                                        \
  gload_lds16(XB + uA##H##0 + (ktv) + vstage, &As[rA(H, 0) * 64]);             \
  gload_lds16(XB + uA##H##1 + (ktv) + vstage, &As[rA(H, 1) * 64]);

#define STAGE_B(H, ktv)                                                        \
  gload_lds16(WT + uB##H + (ktv) + vstage, &Bs[rB(H) * 64]);

// region-local stage rows (wave-uniform, 8-row aligned)
#define rA(H, Q) (((Q)*2 + (wid >> 2)) * 64 + (wid & 3) * 8 + (H)*32)
#define rB(H) ((wid >> 2) * 64 + (wid & 3) * 8 + (H)*32)

#define LOAD_A2(qm)                                                            \
  _Pragma("unroll") for (int mi = 0; mi < 2; ++mi) {                           \
    a[0][mi] = *reinterpret_cast<const short8*>(                               \
        &As[aBase + (qm)*2048 + mi * 1024 + slot0]);                           \
    a[1][mi] = *reinterpret_cast<const short8*>(                               \
        &As[aBase + (qm)*2048 + mi * 1024 + slot1]);                           \
  }

#define LOAD_B2(dst, qn)                                                       \
  _Pragma("unroll") for (int nj = 0; nj < 2; ++nj) {                           \
    dst[0][nj] = *reinterpret_cast<const short8*>(                             \
        &Bs[bBase + (qn)*2048 + nj * 1024 + slot0]);                           \
    dst[1][nj] = *reinterpret_cast<const short8*>(                             \
        &Bs[bBase + (qn)*2048 + nj * 1024 + slot1]);                           \
  }

#define MFMA_PHASE(QM, QN, BF)                                                 \
  __builtin_amdgcn_s_setprio(1);                                               \
  _Pragma("unroll") for (int ks = 0; ks < 2; ++ks)                             \
      _Pragma("unroll") for (int mi = 0; mi < 2; ++mi)                         \
          _Pragma("unroll") for (int nj = 0; nj < 2; ++nj)                     \
              acc[(QM)*2 + mi][(QN)*2 + nj] =                                  \
      MFMA_BF16(a[ks][mi], BF[ks][nj], acc[(QM)*2 + mi][(QN)*2 + nj], 0, 0, 0);\
  __builtin_amdgcn_s_setprio(0);

#define BAR() __builtin_amdgcn_s_barrier()

__global__ __launch_bounds__(512, 4) void gemm_bf16_mp(
    const ushort_t* __restrict__ XB, const ushort_t* __restrict__ WT,
    const float* __restrict__ Y, float* __restrict__ O) {
  __shared__ ushort_t As[256 * 64];  // 32 KB
  __shared__ ushort_t Bs[128 * 64];  // 16 KB

  // block map: xcd = wg&7 owns 4-wide n-band (512 cols), m-fastest.
  // Per-XCD B working set = 4 MB = L2-resident; A shared via L3.
  // Bijective: 8 xcd x 4 n x 32 m = 1024.
  const int wg = blockIdx.x;
  const int xcd = wg & 7;
  const int local = wg >> 3;                      // 0..127
  const int bm0 = (local >> 2) * 256;             // 32 m-tiles, fastest
  const int bn0 = (xcd * 4 + (local & 3)) * 128;  // 4-wide n-band per XCD

  const int tid = threadIdx.x;
  const int lane = tid & 63;
  const int wid = tid >> 6;  // 0..7
  const int wmi = wid >> 1;  // 0..3 (m-band of 64)
  const int wni = wid & 1;   // 0..1 (n-band of 64)

  // staging: per-lane part (1 VGPR) + wave-uniform SGPR stream offsets
  const int l8 = lane >> 3;
  const uint32_t vstage = (uint32_t)l8 * KK + ((lane & 7) ^ l8) * 8;
  const uint32_t uA00 = (uint32_t)(bm0 + rA(0, 0)) * KK;
  const uint32_t uA01 = (uint32_t)(bm0 + rA(0, 1)) * KK;
  const uint32_t uA10 = (uint32_t)(bm0 + rA(1, 0)) * KK;
  const uint32_t uA11 = (uint32_t)(bm0 + rA(1, 1)) * KK;
  const uint32_t uB0 = (uint32_t)(bn0 + rB(0)) * KK;
  const uint32_t uB1 = (uint32_t)(bn0 + rB(1)) * KK;

  // fragment read decomposition (identical slot-XOR family as R0, 0-conflict)
  const int lr = lane & 15, lg = lane >> 4, lr7 = lane & 7;
  const int slot0 = (lg ^ lr7) * 8;        // ks=0, elements
  const int slot1 = ((4 | lg) ^ lr7) * 8;  // ks=1
  const int aBase = (wmi * 64 + lr) * 64;
  const int bBase = (wni * 64 + lr) * 64;

  f32x4 acc[4][4] = {};
  short8 a[2][2], b0[2][2], b1[2][2];

  // ---- prologue: stage t0.{B0, A0, B1}; keep B1 in flight ----
  STAGE_B(0, 0);
  STAGE_A(0, 0);
  STAGE_B(1, 0);
  asm volatile("s_waitcnt vmcnt(1)" ::: "memory");  // B0,A0 landed
  BAR();

#pragma unroll 1
  for (int t = 0; t < NT; ++t) {
    const int kt = t * BK;
    const int k1 = ((t + 1) & (NT - 1)) * BK;
    // ---- p1: quadrant (0,0); stage A1(t) ----
    LOAD_A2(0);
    LOAD_B2(b0, 0);
    STAGE_A(1, kt);
    asm volatile("s_waitcnt lgkmcnt(4)");
    BAR();
    asm volatile("s_waitcnt lgkmcnt(0)");
    MFMA_PHASE(0, 0, b0);
    asm volatile("s_waitcnt vmcnt(2)" ::: "memory");  // B1(t) landed
    BAR();
    // ---- p2: quadrant (0,1); stage B0(t+1) ----
    LOAD_B2(b1, 1);
    STAGE_B(0, k1);
    BAR();
    asm volatile("s_waitcnt lgkmcnt(0)");
    MFMA_PHASE(0, 1, b1);
    asm volatile("s_waitcnt vmcnt(1)" ::: "memory");  // A1(t) landed
    BAR();
    // ---- p3 (merged): quadrants (1,1)+(1,0); stage A0(t+1), B1(t+1) ----
    LOAD_A2(1);
    STAGE_A(0, k1);
    STAGE_B(1, k1);
    asm volatile("s_waitcnt lgkmcnt(4)");
    BAR();
    asm volatile("s_waitcnt lgkmcnt(0)");
    MFMA_PHASE(1, 1, b1);
    MFMA_PHASE(1, 0, b0);
    asm volatile("s_waitcnt vmcnt(1)" ::: "memory");  // B0,A0(t+1) landed
    BAR();
  }

  // epilogue: C/D layout col=lane&15, row=(lane>>4)*4+r  [m89-verified]
  // (outstanding wrapped stage loads write only LDS; drained at endpgm)
#pragma unroll
  for (int i = 0; i < 4; ++i) {
#pragma unroll
    for (int j = 0; j < 4; ++j) {
#pragma unroll
      for (int r = 0; r < 4; ++r) {
        const int grow = bm0 + wmi * 64 + i * 16 + lg * 4 + r;
        const int gcol = bn0 + wni * 64 + j * 16 + lr;
        const size_t idx = (size_t)grow * NN + gcol;
        const float yv = __builtin_nontemporal_load(&Y[idx]);
        __builtin_nontemporal_store(epilogue(acc[i][j][r], yv), &O[idx]);
      }
    }
  }
}

// ---------------- mid-tier (validated R1): reg-staged conversion GEMM ----------------
#define LDP 72
__global__ __launch_bounds__(256, 3) void gemm_fused(
    const float* __restrict__ X, const ushort_t* __restrict__ WT,
    const float* __restrict__ Y, float* __restrict__ O) {
  __shared__ ushort_t Asm[BM * LDP];
  __shared__ ushort_t Bsm[BN * LDP];

  const int nwg = (MM / BM) * (NN / BN);
  int wg = blockIdx.x;
  wg = (wg % 8) * (nwg / 8) + wg / 8;
  const int NTC = NN / BN;
  const int bm0 = (wg / NTC) * BM;
  const int bn0 = (wg % NTC) * BN;

  const int tid = threadIdx.x;
  const int lane = tid & 63;
  const int wid = tid >> 6;
  const int wm = (wid >> 1) * 64, wn = (wid & 1) * 64;
  const int lr = lane & 15, lg = lane >> 4;

  f32x4 acc[4][4] = {};

  const int arow = tid >> 2;
  const int ac = (tid & 3) * 4;
  const int brow = tid >> 1;
  const int bc0 = (tid & 1) * 32;

  for (int kt = 0; kt < KK; kt += BK) {
    __syncthreads();
#pragma unroll
    for (int p = 0; p < 2; ++p) {
      const int row = arow + p * 64;
      const float* src = &X[(size_t)(bm0 + row) * KK + kt];
#pragma unroll
      for (int j = 0; j < 4; ++j) {
        f32x4 v = *reinterpret_cast<const f32x4*>(&src[ac + j * 16]);
        uint2 packed;
        packed.x = (uint32_t)f2bf(v[0]) | ((uint32_t)f2bf(v[1]) << 16);
        packed.y = (uint32_t)f2bf(v[2]) | ((uint32_t)f2bf(v[3]) << 16);
        *reinterpret_cast<uint2*>(&Asm[row * LDP + ac + j * 16]) = packed;
      }
    }
    {
      const ushort_t* src = &WT[(size_t)(bn0 + brow) * KK + kt + bc0];
#pragma unroll
      for (int j = 0; j < 4; ++j) {
        short8 u = *reinterpret_cast<const short8*>(&src[j * 8]);
        *reinterpret_cast<short8*>(&Bsm[brow * LDP + bc0 + j * 8]) = u;
      }
    }
    __syncthreads();

#pragma unroll
    for (int ks = 0; ks < 2; ++ks) {
      short8 a[4], b[4];
#pragma unroll
      for (int i = 0; i < 4; ++i) {
        a[i] = *reinterpret_cast<const short8*>(&Asm[(wm + i * 16 + lr) * LDP + ks * 32 + lg * 8]);
        b[i] = *reinterpret_cast<const short8*>(&Bsm[(wn + i * 16 + lr) * LDP + ks * 32 + lg * 8]);
      }
#pragma unroll
      for (int i = 0; i < 4; ++i)
#pragma unroll
        for (int j = 0; j < 4; ++j)
          acc[i][j] = MFMA_BF16(a[i], b[j], acc[i][j], 0, 0, 0);
    }
  }

#pragma unroll
  for (int i = 0; i < 4; ++i) {
#pragma unroll
    for (int j = 0; j < 4; ++j) {
#pragma unroll
      for (int r = 0; r < 4; ++r) {
        const int grow = bm0 + wm + i * 16 + lg * 4 + r;
        const int gcol = bn0 + wn + j * 16 + lr;
        const size_t idx = (size_t)grow * NN + gcol;
        O[idx] = epilogue(acc[i][j][r], Y[idx]);
      }
    }
  }
}

// ---------------- naive fallback ----------------
__global__ void naive_fused(const float* __restrict__ X, const float* __restrict__ W,
                            const float* __restrict__ Y, float* __restrict__ O) {
  const int n0 = (blockIdx.x * 256 + threadIdx.x) * 4;
  const int m = blockIdx.y;
  f32x4 acc = {0.f, 0.f, 0.f, 0.f};
  const float* xr = &X[(size_t)m * KK];
  for (int k = 0; k < KK; ++k) {
    const float xv = xr[k];
    const f32x4 wv = *reinterpret_cast<const f32x4*>(&W[(size_t)k * NN + n0]);
    acc[0] += xv * wv[0];
    acc[1] += xv * wv[1];
    acc[2] += xv * wv[2];
    acc[3] += xv * wv[3];
  }
  const size_t idx = (size_t)m * NN + n0;
  O[idx + 0] = epilogue(acc[0], Y[idx + 0]);
  O[idx + 1] = epilogue(acc[1], Y[idx + 1]);
  O[idx + 2] = epilogue(acc[2], Y[idx + 2]);
  O[idx + 3] = epilogue(acc[3], Y[idx + 3]);
}

extern "C" void kernel_launch(void* const* d_in, const int* in_sizes, int n_in,
                              void* d_out, int out_size, void* d_ws, size_t ws_size,
                              hipStream_t stream) {
  const float* x = (const float*)d_in[0];
  const float* y = (const float*)d_in[1];
  const float* w = (const float*)d_in[2];
  float* out = (float*)d_out;

  const size_t xb_bytes = (size_t)MM * KK * sizeof(ushort_t);  // 67.1 MB
  const size_t wt_bytes = (size_t)NN * KK * sizeof(ushort_t);  // 33.5 MB

  if (ws_size >= xb_bytes + wt_bytes) {
    ushort_t* XB = (ushort_t*)d_ws;
    ushort_t* WT = (ushort_t*)((char*)d_ws + xb_bytes);
    hipLaunchKernelGGL((prep_kernel<1>), dim3(CVT_BLOCKS + WT_BLOCKS), dim3(256), 0, stream,
                       x, XB, w, WT);
    hipLaunchKernelGGL(gemm_bf16_mp, dim3((MM / 256) * (NN / 128)), dim3(512), 0, stream,
                       XB, WT, y, out);
  } else if (ws_size >= wt_bytes) {
    ushort_t* WT = (ushort_t*)d_ws;
    hipLaunchKernelGGL((prep_kernel<0>), dim3(WT_BLOCKS), dim3(256), 0, stream,
                       x, nullptr, w, WT);
    hipLaunchKernelGGL(gemm_fused, dim3((MM / BM) * (NN / BN)), dim3(256), 0, stream,
                       x, WT, y, out);
  } else {
    hipLaunchKernelGGL(naive_fused, dim3(NN / 1024, MM), dim3(256), 0, stream, x, w, y, out);
  }
}

// Round 5
// 332.149 us; speedup vs baseline: 1.5306x; 1.5306x over previous
//
#include <hip/hip_runtime.h>
#include <hip/hip_bf16.h>
#include <cstdint>

typedef __attribute__((ext_vector_type(8))) short short8;
typedef __attribute__((ext_vector_type(4))) float f32x4;
typedef __attribute__((ext_vector_type(16))) float f32x16;
typedef unsigned short ushort_t;

#define MM 8192
#define NN 4096
#define KK 4096

#define BM 128
#define BN 128
#define BK 64
#define NT (KK / BK)  // 64 K-tiles

#define MFMA_BF16 __builtin_amdgcn_mfma_f32_16x16x32_bf16
#define MFMA32 __builtin_amdgcn_mfma_f32_32x32x16_bf16

// fp32 -> bf16 round-to-nearest-even (inputs are finite)
__device__ __forceinline__ ushort_t f2bf(float f) {
  uint32_t u = __builtin_bit_cast(uint32_t, f);
  u = (u + 0x7FFFu + ((u >> 16) & 1u)) >> 16;
  return (ushort_t)u;
}

// fused activation chain: leaky_relu -> +y -> mish -> hardswish + 0.5
__device__ __forceinline__ float epilogue(float v, float yv) {
  v = fmaxf(v, 0.01f * v);  // leaky relu
  v += yv;
  const float vc = fminf(v, 15.f);
  const float t = __builtin_amdgcn_exp2f(vc * 1.44269504f);  // e^vc
  const float d = t * t + 2.f * t;
  const float mi = v * d * __builtin_amdgcn_rcpf(d + 2.f);   // mish
  const float r6 = fminf(fmaxf(mi + 3.f, 0.f), 6.f);
  return mi * r6 * (1.f / 6.f) + 0.5f;                       // hardswish + 0.5
}

// async 16B global->LDS (LDS dest is wave-uniform base + lane*16)
__device__ __forceinline__ void gload_lds16(const void* g, void* l) {
  __builtin_amdgcn_global_load_lds(
      (const __attribute__((address_space(1))) unsigned int*)g,
      (__attribute__((address_space(3))) unsigned int*)l, 16, 0, 0);
}

#define CVT_BLOCKS ((MM * KK) / (256 * 8))      // 16384
#define WT_BLOCKS ((NN / 32) * (KK / 32))       // 16384

// ---------------- merged prep: X convert (bid<CVT_BLOCKS) + W transpose ----------------
template <int DO_X>
__global__ void prep_kernel(const float* __restrict__ X, ushort_t* __restrict__ XB,
                            const float* __restrict__ W, ushort_t* __restrict__ WT) {
  __shared__ float t[32][33];
  const int bid = blockIdx.x;
  const int tid = threadIdx.x;
  if (DO_X && bid < CVT_BLOCKS) {
    const size_t i = ((size_t)bid * 256 + tid) * 8;
    f32x4 v0 = __builtin_nontemporal_load(reinterpret_cast<const f32x4*>(&X[i]));
    f32x4 v1 = __builtin_nontemporal_load(reinterpret_cast<const f32x4*>(&X[i + 4]));
    short8 o;
    o[0] = (short)f2bf(v0[0]); o[1] = (short)f2bf(v0[1]);
    o[2] = (short)f2bf(v0[2]); o[3] = (short)f2bf(v0[3]);
    o[4] = (short)f2bf(v1[0]); o[5] = (short)f2bf(v1[1]);
    o[6] = (short)f2bf(v1[2]); o[7] = (short)f2bf(v1[3]);
    *reinterpret_cast<short8*>(&XB[i]) = o;
  } else {
    const int b2 = DO_X ? (bid - CVT_BLOCKS) : bid;
    const int n0 = (b2 & 127) * 32, k0 = (b2 >> 7) * 32;
    const int tx = tid & 31, ty = tid >> 5;  // 32 x 8
#pragma unroll
    for (int i = ty; i < 32; i += 8)
      t[i][tx] = __builtin_nontemporal_load(&W[(size_t)(k0 + i) * NN + n0 + tx]);
    __syncthreads();
#pragma unroll
    for (int i = ty; i < 32; i += 8)
      WT[(size_t)(n0 + i) * KK + k0 + tx] = f2bf(t[tx][i]);
  }
}

// ---------------- main fused GEMM: 256x256, 32x32x16 MFMA, dbuf prefetch --------------
// R5. Evidence R0-R4: every non-spilling variant = LDS-read + MFMA serial sum
// (R0 287us = 132 MFMA + 160 LDS; R1-3 290 = 132 + 120 + barrier jitter).
// Levers: (1) 32x32x16 MFMA (ubench 2382 vs 2075 TF -> MFMA floor 132->115us);
// (2) 256^2 tile (LDS floor 160->120us); (3) ZERO intra-tile barriers + dbuf
// prefetch: stage t+1 issued BEFORE the ~4000-cyc compute, single
// __syncthreads per K-tile whose vmcnt drain is hidden by construction; the
// barrier-free window lets the 2 waves/SIMD drift -> ds_read || MFMA overlap.
// (4) launch_bounds(512,2) -> 256 regs/wave; live ~190 (acc 128 + frags 24 +
// addr) -> NO cap saturation (R4's spill lesson; tripwire = WRITE_SIZE).
//
// Hazards (one barrier per tile suffices): stage(t+1)->buf[c^1] happens after
// sync(t-1) which drained all reads of buf[c^1] (read at t-1); compute(t)
// reads buf[c]; sync(t) drains stage vmcnt before t+1 reads buf[c^1]. Tail
// stage wraps mod K (wasted, hazard-free).
//
// 32x32x16 fragment maps: A: lane l holds A[l&31][(l>>5)*8+j] (family pattern,
// forced by 4-VGPR operand); B: B[(l>>5)*8+j][l&31]; C/D: col=lane&31,
// row=(reg&3)+8*(reg>>2)+4*(lane>>5) [m74/m101 HW-verified]. LDS swizzle
// unchanged: LDS[row][slot ^ (row&7)], reads 2-way max per quarter-wave = free.
#define HB 32768  // elems per buffer (A 16384 | B 16384)

#define STAGE(base, kt)                                                        \
  _Pragma("unroll") for (int c = 0; c < 4; ++c) {                              \
    gload_lds16(XB + offA[c] + (kt), (base) + (wid * 8 + c * 64) * 64);        \
    gload_lds16(WT + offB[c] + (kt),                                           \
                (base) + 16384 + (wid * 8 + c * 64) * 64);                     \
  }

__global__ __launch_bounds__(512, 2) void gemm_bf16_v5(
    const ushort_t* __restrict__ XB, const ushort_t* __restrict__ WT,
    const float* __restrict__ Y, float* __restrict__ O) {
  __shared__ ushort_t sh[2 * HB];  // 128 KB

  // block map: xcd = wg&7 owns n-band of 2 tiles (512 cols), m-fastest.
  // Per-XCD B working set = 4 MB = L2-resident; A shared via L3.
  // Bijective: 8 xcd x 2 n x 32 m = 512.
  const int wg = blockIdx.x;
  const int xcd = wg & 7;
  const int local = wg >> 3;                     // 0..63
  const int bm0 = (local >> 1) * 256;            // 32 m-tiles, fastest
  const int bn0 = (xcd * 2 + (local & 1)) * 256; // 2-wide n-band per XCD

  const int tid = threadIdx.x;
  const int lane = tid & 63;
  const int wid = tid >> 6;  // 0..7
  const int wmi = wid >> 2;  // 0..1 (M band of 128)
  const int wni = wid & 3;   // 0..3 (N band of 64)

  // staging: pre-swizzled source slot, linear LDS dest
  const int l8 = lane >> 3;
  const uint32_t vsw = (uint32_t)l8 * KK + ((lane & 7) ^ l8) * 8;
  uint32_t offA[4], offB[4];
#pragma unroll
  for (int c = 0; c < 4; ++c) {
    offA[c] = (uint32_t)(bm0 + wid * 8 + c * 64) * KK + vsw;
    offB[c] = (uint32_t)(bn0 + wid * 8 + c * 64) * KK + vsw;
  }

  // fragment read decomposition (32x32 maps)
  const int l31 = lane & 31, kh = lane >> 5, l7 = lane & 7;
  const int aBase = (wmi * 128 + l31) * 64;          // + mf*2048
  const int bBase = 16384 + (wni * 64 + l31) * 64;   // + nf*2048
  int sl[4];
#pragma unroll
  for (int ks = 0; ks < 4; ++ks) sl[ks] = ((ks * 2 + kh) ^ l7) * 8;

  f32x16 acc[4][2] = {};

  // ---- prologue: stage tile 0 into buf 0 ----
  STAGE(sh, 0);
  __syncthreads();

#pragma unroll 1
  for (int t = 0; t < NT; ++t) {
    ushort_t* cur = sh + (t & 1) * HB;
    ushort_t* nxt = sh + ((t + 1) & 1) * HB;
    const int k1 = ((t + 1) & (NT - 1)) * BK;
    STAGE(nxt, k1);  // prefetch: lands during compute below
#pragma unroll
    for (int ks = 0; ks < 4; ++ks) {
      short8 av[4], bv[2];
#pragma unroll
      for (int mf = 0; mf < 4; ++mf)
        av[mf] = *reinterpret_cast<const short8*>(&cur[aBase + mf * 2048 + sl[ks]]);
#pragma unroll
      for (int nf = 0; nf < 2; ++nf)
        bv[nf] = *reinterpret_cast<const short8*>(&cur[bBase + nf * 2048 + sl[ks]]);
#pragma unroll
      for (int mf = 0; mf < 4; ++mf)
#pragma unroll
        for (int nf = 0; nf < 2; ++nf)
          acc[mf][nf] = MFMA32(av[mf], bv[nf], acc[mf][nf], 0, 0, 0);
    }
    __syncthreads();  // drains stage (old) + fences buffer swap
  }

  // epilogue: 32x32 C/D layout col=lane&31, row=(reg&3)+8*(reg>>2)+4*kh
#pragma unroll
  for (int mf = 0; mf < 4; ++mf) {
#pragma unroll
    for (int nf = 0; nf < 2; ++nf) {
#pragma unroll
      for (int r = 0; r < 16; ++r) {
        const int grow = bm0 + wmi * 128 + mf * 32 + (r & 3) + 8 * (r >> 2) + 4 * kh;
        const int gcol = bn0 + wni * 64 + nf * 32 + l31;
        const size_t idx = (size_t)grow * NN + gcol;
        const float yv = __builtin_nontemporal_load(&Y[idx]);
        __builtin_nontemporal_store(epilogue(acc[mf][nf][r], yv), &O[idx]);
      }
    }
  }
}

// ---------------- mid-tier (validated R1): reg-staged conversion GEMM ----------------
#define LDP 72
__global__ __launch_bounds__(256, 3) void gemm_fused(
    const float* __restrict__ X, const ushort_t* __restrict__ WT,
    const float* __restrict__ Y, float* __restrict__ O) {
  __shared__ ushort_t Asm[BM * LDP];
  __shared__ ushort_t Bsm[BN * LDP];

  const int nwg = (MM / BM) * (NN / BN);
  int wg = blockIdx.x;
  wg = (wg % 8) * (nwg / 8) + wg / 8;
  const int NTC = NN / BN;
  const int bm0 = (wg / NTC) * BM;
  const int bn0 = (wg % NTC) * BN;

  const int tid = threadIdx.x;
  const int lane = tid & 63;
  const int wid = tid >> 6;
  const int wm = (wid >> 1) * 64, wn = (wid & 1) * 64;
  const int lr = lane & 15, lg = lane >> 4;

  f32x4 acc[4][4] = {};

  const int arow = tid >> 2;
  const int ac = (tid & 3) * 4;
  const int brow = tid >> 1;
  const int bc0 = (tid & 1) * 32;

  for (int kt = 0; kt < KK; kt += BK) {
    __syncthreads();
#pragma unroll
    for (int p = 0; p < 2; ++p) {
      const int row = arow + p * 64;
      const float* src = &X[(size_t)(bm0 + row) * KK + kt];
#pragma unroll
      for (int j = 0; j < 4; ++j) {
        f32x4 v = *reinterpret_cast<const f32x4*>(&src[ac + j * 16]);
        uint2 packed;
        packed.x = (uint32_t)f2bf(v[0]) | ((uint32_t)f2bf(v[1]) << 16);
        packed.y = (uint32_t)f2bf(v[2]) | ((uint32_t)f2bf(v[3]) << 16);
        *reinterpret_cast<uint2*>(&Asm[row * LDP + ac + j * 16]) = packed;
      }
    }
    {
      const ushort_t* src = &WT[(size_t)(bn0 + brow) * KK + kt + bc0];
#pragma unroll
      for (int j = 0; j < 4; ++j) {
        short8 u = *reinterpret_cast<const short8*>(&src[j * 8]);
        *reinterpret_cast<short8*>(&Bsm[brow * LDP + bc0 + j * 8]) = u;
      }
    }
    __syncthreads();

#pragma unroll
    for (int ks = 0; ks < 2; ++ks) {
      short8 a[4], b[4];
#pragma unroll
      for (int i = 0; i < 4; ++i) {
        a[i] = *reinterpret_cast<const short8*>(&Asm[(wm + i * 16 + lr) * LDP + ks * 32 + lg * 8]);
        b[i] = *reinterpret_cast<const short8*>(&Bsm[(wn + i * 16 + lr) * LDP + ks * 32 + lg * 8]);
      }
#pragma unroll
      for (int i = 0; i < 4; ++i)
#pragma unroll
        for (int j = 0; j < 4; ++j)
          acc[i][j] = MFMA_BF16(a[i], b[j], acc[i][j], 0, 0, 0);
    }
  }

#pragma unroll
  for (int i = 0; i < 4; ++i) {
#pragma unroll
    for (int j = 0; j < 4; ++j) {
#pragma unroll
      for (int r = 0; r < 4; ++r) {
        const int grow = bm0 + wm + i * 16 + lg * 4 + r;
        const int gcol = bn0 + wn + j * 16 + lr;
        const size_t idx = (size_t)grow * NN + gcol;
        O[idx] = epilogue(acc[i][j][r], Y[idx]);
      }
    }
  }
}

// ---------------- naive fallback ----------------
__global__ void naive_fused(const float* __restrict__ X, const float* __restrict__ W,
                            const float* __restrict__ Y, float* __restrict__ O) {
  const int n0 = (blockIdx.x * 256 + threadIdx.x) * 4;
  const int m = blockIdx.y;
  f32x4 acc = {0.f, 0.f, 0.f, 0.f};
  const float* xr = &X[(size_t)m * KK];
  for (int k = 0; k < KK; ++k) {
    const float xv = xr[k];
    const f32x4 wv = *reinterpret_cast<const f32x4*>(&W[(size_t)k * NN + n0]);
    acc[0] += xv * wv[0];
    acc[1] += xv * wv[1];
    acc[2] += xv * wv[2];
    acc[3] += xv * wv[3];
  }
  const size_t idx = (size_t)m * NN + n0;
  O[idx + 0] = epilogue(acc[0], Y[idx + 0]);
  O[idx + 1] = epilogue(acc[1], Y[idx + 1]);
  O[idx + 2] = epilogue(acc[2], Y[idx + 2]);
  O[idx + 3] = epilogue(acc[3], Y[idx + 3]);
}

extern "C" void kernel_launch(void* const* d_in, const int* in_sizes, int n_in,
                              void* d_out, int out_size, void* d_ws, size_t ws_size,
                              hipStream_t stream) {
  const float* x = (const float*)d_in[0];
  const float* y = (const float*)d_in[1];
  const float* w = (const float*)d_in[2];
  float* out = (float*)d_out;

  const size_t xb_bytes = (size_t)MM * KK * sizeof(ushort_t);  // 67.1 MB
  const size_t wt_bytes = (size_t)NN * KK * sizeof(ushort_t);  // 33.5 MB

  if (ws_size >= xb_bytes + wt_bytes) {
    ushort_t* XB = (ushort_t*)d_ws;
    ushort_t* WT = (ushort_t*)((char*)d_ws + xb_bytes);
    hipLaunchKernelGGL((prep_kernel<1>), dim3(CVT_BLOCKS + WT_BLOCKS), dim3(256), 0, stream,
                       x, XB, w, WT);
    hipLaunchKernelGGL(gemm_bf16_v5, dim3((MM / 256) * (NN / 256)), dim3(512), 0, stream,
                       XB, WT, y, out);
  } else if (ws_size >= wt_bytes) {
    ushort_t* WT = (ushort_t*)d_ws;
    hipLaunchKernelGGL((prep_kernel<0>), dim3(WT_BLOCKS), dim3(256), 0, stream,
                       x, nullptr, w, WT);
    hipLaunchKernelGGL(gemm_fused, dim3((MM / BM) * (NN / BN)), dim3(256), 0, stream,
                       x, WT, y, out);
  } else {
    hipLaunchKernelGGL(naive_fused, dim3(NN / 1024, MM), dim3(256), 0, stream, x, w, y, out);
  }
}